// Round 14
// baseline (303.087 us; speedup 1.0000x reference)
//
#include <hip/hip_runtime.h>
#include <cstdint>

#define HEXP 10.0f
#define LN2 0.69314718056f
#define RLN2 1.44269504089f
#define QSCALE 500.0f

__device__ __forceinline__ float hw_log2(float x) { return __builtin_amdgcn_logf(x); }
__device__ __forceinline__ float hw_exp2(float x) { return __builtin_amdgcn_exp2f(x); }
__device__ __forceinline__ float hw_rcp(float x) { return __builtin_amdgcn_rcpf(x); }

typedef int i32x4 __attribute__((ext_vector_type(4)));

__device__ __forceinline__ void gl_lds16(const void* g, void* l) {
  __builtin_amdgcn_global_load_lds(
      (const __attribute__((address_space(1))) void*)g,
      (__attribute__((address_space(3))) void*)l, 16, 0, 0);
}

#define BAR() asm volatile("s_barrier" ::: "memory")
#define VM3() asm volatile("s_waitcnt vmcnt(3)" ::: "memory")
#define VM0() asm volatile("s_waitcnt vmcnt(0)" ::: "memory")

// ------- row L2-normalize f32 -> int8 (x QSCALE), PLAIN row-major -------
// |xn_i| <= ~0.17 -> q <= ~87 << 127; dot exact in int32 (<= 7.7M < 2^24).
__global__ __launch_bounds__(256) void k_rownorm(const float* __restrict__ in,
                                                 unsigned char* __restrict__ out,
                                                 int D) {
  const int row = blockIdx.x;
  const int tid = threadIdx.x;
  const float4* inr = (const float4*)(in + (size_t)row * D);
  float4 v = inr[tid];
  float ss = v.x * v.x + v.y * v.y + v.z * v.z + v.w * v.w;
#pragma unroll
  for (int off = 32; off >= 1; off >>= 1) ss += __shfl_xor(ss, off, 64);
  __shared__ float s4[4];
  if ((tid & 63) == 0) s4[tid >> 6] = ss;
  __syncthreads();
  float tot = s4[0] + s4[1] + s4[2] + s4[3];
  float scale = QSCALE / fmaxf(sqrtf(tot), 1e-12f);
  int q0 = __float2int_rn(fmaxf(-127.f, fminf(127.f, v.x * scale)));
  int q1 = __float2int_rn(fmaxf(-127.f, fminf(127.f, v.y * scale)));
  int q2 = __float2int_rn(fmaxf(-127.f, fminf(127.f, v.z * scale)));
  int q3 = __float2int_rn(fmaxf(-127.f, fminf(127.f, v.w * scale)));
  int w0 = (q0 & 0xff) | ((q1 & 0xff) << 8) | ((q2 & 0xff) << 16) | (q3 << 24);
  *(int*)(out + (size_t)row * D + tid * 4) = w0;
}

// ------- fused i8 GEMM (exact int32 dot) + harmonic-softmax partials -------
// R13 was latency-bound: all pipes ~30%, 12 waves/CU. This round: FOUR
// co-resident blocks/CU (4 independent barrier groups, 16 waves/CU).
// Enablers: per-wave tile 64x32 -> acc[4][2] = 32 AGPR; total regs ~105
// under the 128 cap from __launch_bounds__(256,4) (margin ~23 — R9's
// failure was margin -90); LDS ring-3 x (A 8KB + B 4KB) = 36KB -> 4 by LDS.
// Proven pieces verbatim: zero-conflict chunk geometry (R11/R13: row stride
// 64B, slot16 = (kq^((fcol>>1)&3))<<4, share-lanes 512B apart), rule-#21
// staging decode, VM-counted-before-BAR ring-3 calendar, setprio, XCD swizzle.
__global__ __launch_bounds__(256, 4) void k_gemm_lse(
    const unsigned char* __restrict__ xnb,
    const unsigned char* __restrict__ wnb,
    const int* __restrict__ tgt,
    float* __restrict__ parts,
    float* __restrict__ tlp,
    int M, int C, int D, int ntN) {
  __shared__ __align__(16) unsigned char sA[3][8192];  // 128r x 64k i8
  __shared__ __align__(16) unsigned char sB[3][4096];  // 64c  x 64k i8
  __shared__ int s_tgt[128];

  const int ntM = M >> 7;               // 32
  const int nwg = ntM * ntN;            // 16000 (div by 8)
  const int orig = blockIdx.x;
  const int cpx = nwg >> 3;
  const int bid = (orig & 7) * cpx + (orig >> 3);   // bijective XCD swizzle
  const int tileM = bid % ntM;
  const int tileN = bid / ntM;
  const int row0 = tileM << 7;
  const int c0 = tileN << 6;

  const int tid = threadIdx.x;
  const int lane = tid & 63;
  const int wid = tid >> 6;             // 0..3
  const int wr = wid >> 1;              // M-half (64 rows)
  const int wc = wid & 1;               // N-half (32 cols)
  const int fcol = lane & 15;
  const int kq = lane >> 4;

  if (tid < 128) s_tgt[tid] = tgt[row0 + tid];

  // staging lane constants (rule #21 decode, R11/R13 verbatim)
  const int srow_l = lane >> 2;
  const int scol_l = (((lane & 3) ^ ((lane >> 3) & 3)) << 4);
  const int lane16 = lane << 4;
  const size_t Dz = (size_t)D;  // row stride bytes

  // A: wave stages 32 rows (2 x 1KB chunks); B: wave stages 16 rows (1 chunk)
#define STAGE_A(ds, kb)                                                        \
  do {                                                                         \
    gl_lds16(xnb + (size_t)(row0 + (wid << 5) + srow_l) * Dz + (kb) + scol_l,  \
             sA[ds] + (wid << 11) + lane16);                                   \
    gl_lds16(xnb + (size_t)(row0 + (wid << 5) + 16 + srow_l) * Dz + (kb) +     \
                 scol_l,                                                       \
             sA[ds] + (wid << 11) + 1024 + lane16);                            \
  } while (0)
#define STAGE_B(ds, kb)                                                        \
  gl_lds16(wnb + (size_t)(c0 + (wid << 4) + srow_l) * Dz + (kb) + scol_l,      \
           sB[ds] + (wid << 10) + lane16)

  // fragment read bases (bytes); per-frag (16-row) stride 1024
  const int slot16 = ((kq ^ ((fcol >> 1) & 3)) << 4);
  const int abase = (wr * 64 + fcol) * 64 + slot16;
  const int bbase = (wc * 32 + fcol) * 64 + slot16;

  i32x4 acc[4][2];
#pragma unroll
  for (int m = 0; m < 4; ++m)
#pragma unroll
    for (int n = 0; n < 2; ++n) acc[m][n] = (i32x4){0, 0, 0, 0};

  i32x4 av[4], bv[2];
  const int NT = D >> 6;  // 16

  // prologue: stage tiles 0,1 (3 loads each per wave)
  STAGE_A(0, 0);
  STAGE_B(0, 0);
  STAGE_A(1, 64);
  STAGE_B(1, 64);

#pragma unroll
  for (int t = 0; t < 16; ++t) {
    // cert slot t: allow only stage(t+1)'s 3 loads to remain pending.
    if (t + 1 < NT) VM3();
    else VM0();
    BAR();  // all waves' stage(t) landed; slot (t+2)%3 old readers done
    if (t + 2 < NT) {
      STAGE_A((t + 2) % 3, (t + 2) * 64);
      STAGE_B((t + 2) % 3, (t + 2) * 64);
    }
    {
      const unsigned char* pA_ = sA[t % 3];
      const unsigned char* pB_ = sB[t % 3];
#pragma unroll
      for (int mm = 0; mm < 4; ++mm)
        av[mm] = *(const i32x4*)(pA_ + abase + mm * 1024);
#pragma unroll
      for (int n = 0; n < 2; ++n)
        bv[n] = *(const i32x4*)(pB_ + bbase + n * 1024);
    }
    __builtin_amdgcn_s_setprio(1);
#pragma unroll
    for (int mm = 0; mm < 4; ++mm)
#pragma unroll
      for (int n = 0; n < 2; ++n)
        acc[mm][n] = __builtin_amdgcn_mfma_i32_16x16x64_i8(
            av[mm], bv[n], acc[mm][n], 0, 0, 0);
    __builtin_amdgcn_s_setprio(0);
  }

  // ---- epilogue: t2 = 2 - 2*dot/S^2; se-term = t2^-5 = d^-10 ----
  // C/D: col = fcol, row = kq*4 + j per 16x16 fragment (dtype-independent).
#pragma unroll
  for (int m = 0; m < 4; ++m) {
#pragma unroll
    for (int j = 0; j < 4; ++j) {
      const int rl = wr * 64 + m * 16 + kq * 4 + j;
      const int grow = row0 + rl;
      const int trow = s_tgt[rl];
      float se = 0.f;
#pragma unroll
      for (int n = 0; n < 2; ++n) {
        float dotf = (float)acc[m][n][j];
        float t2 = fmaxf(fmaf(dotf, -2.f / (QSCALE * QSCALE), 2.f), 1e-6f);
        float r = hw_rcp(t2);
        float r2 = r * r;
        float r4 = r2 * r2;
        se += r4 * r;  // t2^-5
        int col = c0 + wc * 32 + n * 16 + fcol;
        if (col == trow) tlp[grow] = (-HEXP * LN2) * hw_log2(sqrtf(t2) + 1e-8f);
      }
#pragma unroll
      for (int off = 8; off >= 1; off >>= 1) se += __shfl_xor(se, off, 64);
      if (fcol == 0) parts[(size_t)grow * (ntN * 2) + tileN * 2 + wc] = se;
    }
  }
}

// ---------------- per-row sum of linear partials + loss ----------------
__global__ __launch_bounds__(256) void k_combine(const float* __restrict__ parts,
                                                 const float* __restrict__ tlp,
                                                 float* __restrict__ rloss, int P) {
  const int row = blockIdx.x;
  const int tid = threadIdx.x;
  const float* p = parts + (size_t)row * P;
  float s = 0.f;
  for (int i = tid; i < P; i += 256) s += p[i];
#pragma unroll
  for (int off = 32; off >= 1; off >>= 1) s += __shfl_xor(s, off, 64);
  __shared__ float ssum[4];
  if ((tid & 63) == 0) ssum[tid >> 6] = s;
  __syncthreads();
  if (tid == 0) {
    float tot = ssum[0] + ssum[1] + ssum[2] + ssum[3];
    float lse = hw_log2(tot) * LN2;
    float pt = hw_exp2((tlp[row] - lse) * RLN2);
    rloss[row] = -hw_log2(pt + 1e-8f) * LN2;
  }
}

// ---------------- mean over rows ----------------
__global__ __launch_bounds__(256) void k_mean(const float* __restrict__ rloss,
                                              float* __restrict__ out, int B) {
  const int tid = threadIdx.x;
  double s = 0.0;
  for (int i = tid; i < B; i += 256) s += (double)rloss[i];
#pragma unroll
  for (int off = 32; off >= 1; off >>= 1) s += __shfl_xor(s, off, 64);
  __shared__ double sd[4];
  if ((tid & 63) == 0) sd[tid >> 6] = s;
  __syncthreads();
  if (tid == 0) out[0] = (float)((sd[0] + sd[1] + sd[2] + sd[3]) / (double)B);
}

extern "C" void kernel_launch(void* const* d_in, const int* in_sizes, int n_in,
                              void* d_out, int out_size, void* d_ws, size_t ws_size,
                              hipStream_t stream) {
  const float* x = (const float*)d_in[0];
  const float* w = (const float*)d_in[1];
  const int* tg = (const int*)d_in[2];
  const int B = in_sizes[2];
  const int D = in_sizes[0] / B;       // 1024
  const int C = in_sizes[1] / D;       // 32000
  const int ntN = C / 64;              // 500

  char* ws = (char*)d_ws;
  unsigned char* xnb = (unsigned char*)ws;                   // B*D i8
  unsigned char* wnb = xnb + (size_t)B * D;                  // C*D i8
  size_t off = (size_t)B * D + (size_t)C * D;
  off = (off + 255) & ~(size_t)255;
  float* parts = (float*)(ws + off);                         // B * ntN * 2
  off += (size_t)B * ntN * 2 * sizeof(float);
  float* tlp = (float*)(ws + off);                           // B
  off += (size_t)B * sizeof(float);
  float* rloss = (float*)(ws + off);                         // B

  k_rownorm<<<B, 256, 0, stream>>>(x, xnb, D);
  k_rownorm<<<C, 256, 0, stream>>>(w, wnb, D);
  k_gemm_lse<<<(B / 128) * ntN, 256, 0, stream>>>(xnb, wnb, tg, parts, tlp, B, C, D, ntN);
  k_combine<<<B, 256, 0, stream>>>(parts, tlp, rloss, ntN * 2);
  k_mean<<<1, 256, 0, stream>>>(rloss, (float*)d_out, B);
}

// Round 15
// 237.677 us; speedup vs baseline: 1.2752x; 1.2752x over previous
//
#include <hip/hip_runtime.h>
#include <cstdint>

#define HEXP 10.0f
#define LN2 0.69314718056f
#define RLN2 1.44269504089f
#define QSCALE 500.0f

__device__ __forceinline__ float hw_log2(float x) { return __builtin_amdgcn_logf(x); }
__device__ __forceinline__ float hw_exp2(float x) { return __builtin_amdgcn_exp2f(x); }
__device__ __forceinline__ float hw_rcp(float x) { return __builtin_amdgcn_rcpf(x); }

typedef int i32x4 __attribute__((ext_vector_type(4)));

__device__ __forceinline__ void gl_lds16(const void* g, void* l) {
  __builtin_amdgcn_global_load_lds(
      (const __attribute__((address_space(1))) void*)g,
      (__attribute__((address_space(3))) void*)l, 16, 0, 0);
}

#define BAR() asm volatile("s_barrier" ::: "memory")
#define VM6() asm volatile("s_waitcnt vmcnt(6)" ::: "memory")
#define VM0() asm volatile("s_waitcnt vmcnt(0)" ::: "memory")

// ---- shared normalize+quantize helper (int8, x QSCALE) ----
// |xn_i| <= ~0.17 -> q <= ~87 << 127; dot exact in int32 (<= 7.7M < 2^24).
__device__ __forceinline__ int norm_quant(const float* in, int D, int row,
                                          int tid, float* s4) {
  const float4* inr = (const float4*)(in + (size_t)row * D);
  float4 v = inr[tid];
  float ss = v.x * v.x + v.y * v.y + v.z * v.z + v.w * v.w;
#pragma unroll
  for (int off = 32; off >= 1; off >>= 1) ss += __shfl_xor(ss, off, 64);
  if ((tid & 63) == 0) s4[tid >> 6] = ss;
  __syncthreads();
  float tot = s4[0] + s4[1] + s4[2] + s4[3];
  float scale = QSCALE / fmaxf(sqrtf(tot), 1e-12f);
  int q0 = __float2int_rn(fmaxf(-127.f, fminf(127.f, v.x * scale)));
  int q1 = __float2int_rn(fmaxf(-127.f, fminf(127.f, v.y * scale)));
  int q2 = __float2int_rn(fmaxf(-127.f, fminf(127.f, v.z * scale)));
  int q3 = __float2int_rn(fmaxf(-127.f, fminf(127.f, v.w * scale)));
  return (q0 & 0xff) | ((q1 & 0xff) << 8) | ((q2 & 0xff) << 16) | (q3 << 24);
}

// ------- x rows -> FRAGMENT-MAJOR global A' -------
// A'[(row>>4)][k>>6][kq=(k>>4)&3][fcol=row&15][j=k&15]: each (16-row,64-k)
// tile stored so the wave A-operand (lane = kq*16+fcol reads 16B) is the
// contiguous 1KB at blockbase + lane*16 -> perfectly coalesced global load.
__global__ __launch_bounds__(256) void k_rownorm_x(const float* __restrict__ in,
                                                   unsigned char* __restrict__ out,
                                                   int D) {
  const int row = blockIdx.x;
  const int tid = threadIdx.x;
  __shared__ float s4[4];
  int w0 = norm_quant(in, D, row, tid, s4);
  const int k0 = tid * 4;
  const size_t doff = (size_t)(row >> 4) * (16 * D) + ((k0 >> 6) << 10) +
                      (((k0 >> 4) & 3) << 8) + ((row & 15) << 4) + (k0 & 15);
  *(int*)(out + doff) = w0;
}

// ------- w rows -> plain row-major (B path unchanged, R13 verbatim) -------
__global__ __launch_bounds__(256) void k_rownorm_w(const float* __restrict__ in,
                                                   unsigned char* __restrict__ out,
                                                   int D) {
  const int row = blockIdx.x;
  const int tid = threadIdx.x;
  __shared__ float s4[4];
  int w0 = norm_quant(in, D, row, tid, s4);
  *(int*)(out + (size_t)row * D + tid * 4) = w0;
}

// ------- fused i8 GEMM + harmonic-softmax partials -------
// R13 structure (128x128 tile, 4 waves 2Mx2N, 3 blocks/CU, ring-3 calendar,
// setprio, XCD swizzle) with A REMOVED FROM LDS: A operands load straight
// from fragment-major global into VGPRs, double-buffered 2 tiles ahead
// (in-flight ~2 tile periods >> L2 latency). B keeps the measured-0-conflict
// LDS machinery verbatim. Halves LDS writes and ds_reads per tile.
// FIFO vmcnt calendar: each body issues B(t+2) [2 loads] then av(t+2) [4];
// at top of tile t the oldest-beyond-6 are exactly B(t)+av(t) -> VM6 certifies
// both (VM0 at tails). BAR makes it cross-wave for B.
__global__ __launch_bounds__(256, 3) void k_gemm_lse(
    const unsigned char* __restrict__ xnb,   // fragment-major A'
    const unsigned char* __restrict__ wnb,   // plain row-major
    const int* __restrict__ tgt,
    float* __restrict__ parts,
    float* __restrict__ tlp,
    int M, int C, int D, int ntN) {
  __shared__ __align__(16) unsigned char sB[3][8192];  // 128c x 64k i8
  __shared__ int s_tgt[128];

  const int ntM = M >> 7;               // 32
  const int nwg = ntM * ntN;            // 8000 (div by 8)
  const int orig = blockIdx.x;
  const int cpx = nwg >> 3;
  const int bid = (orig & 7) * cpx + (orig >> 3);   // bijective XCD swizzle
  const int tileM = bid % ntM;
  const int tileN = bid / ntM;
  const int row0 = tileM << 7;
  const int c0 = tileN << 7;

  const int tid = threadIdx.x;
  const int lane = tid & 63;
  const int wid = tid >> 6;             // 0..3
  const int wr = wid >> 1;              // M-half (64 rows)
  const int wc = wid & 1;               // N-half (64 cols)
  const int fcol = lane & 15;
  const int kq = lane >> 4;

  if (tid < 128) s_tgt[tid] = tgt[row0 + tid];

  // B staging lane constants (rule #21 decode, R11/R13 verbatim)
  const int srow_l = lane >> 2;
  const int scol_l = (((lane & 3) ^ ((lane >> 3) & 3)) << 4);
  const int lane16 = lane << 4;
  const size_t Dz = (size_t)D;

#define STAGE_B(ds, kb)                                                        \
  do {                                                                         \
    gl_lds16(wnb + (size_t)(c0 + (wid << 5) + srow_l) * Dz + (kb) + scol_l,    \
             sB[ds] + (wid << 11) + lane16);                                   \
    gl_lds16(wnb + (size_t)(c0 + (wid << 5) + 16 + srow_l) * Dz + (kb) +       \
                 scol_l,                                                       \
             sB[ds] + (wid << 11) + 1024 + lane16);                            \
  } while (0)

  // B fragment read base (zero-conflict geometry, R11/R13 verbatim)
  const int slot16 = ((kq ^ ((fcol >> 1) & 3)) << 4);
  const int bbase = (wc * 64 + fcol) * 64 + slot16;

  // A' direct-load base: frag (row-block tileM*8 + wr*4 + mm, k-tile t) at
  // base + mm*16*D + t*1024 + lane*16  (contiguous 1KB per wave-instr)
  const unsigned char* apan =
      xnb + (size_t)(tileM * 8 + wr * 4) * (16 * D) + lane16;

  i32x4 acc[4][4];
#pragma unroll
  for (int m = 0; m < 4; ++m)
#pragma unroll
    for (int n = 0; n < 4; ++n) acc[m][n] = (i32x4){0, 0, 0, 0};

  i32x4 avA[4], avB[4], bv[4];
  const int NT = D >> 6;  // 16

  // prologue (FIFO order B,av per tile): B(0), av(0)->avA, B(1), av(1)->avB
  STAGE_B(0, 0);
#pragma unroll
  for (int mm = 0; mm < 4; ++mm)
    avA[mm] = *(const i32x4*)(apan + (size_t)mm * (16 * D));
  STAGE_B(1, 64);
#pragma unroll
  for (int mm = 0; mm < 4; ++mm)
    avB[mm] = *(const i32x4*)(apan + (size_t)mm * (16 * D) + 1024);

#define TILE(t, CUR)                                                           \
  do {                                                                         \
    if ((t) + 1 < NT) VM6();                                                   \
    else VM0();                                                                \
    BAR();                                                                     \
    if ((t) + 2 < NT) STAGE_B(((t) + 2) % 3, ((t) + 2) * 64);                  \
    {                                                                          \
      const unsigned char* pB_ = sB[(t) % 3];                                  \
      _Pragma("unroll") for (int n = 0; n < 4; ++n)                            \
          bv[n] = *(const i32x4*)(pB_ + bbase + n * 1024);                     \
    }                                                                          \
    __builtin_amdgcn_s_setprio(1);                                             \
    _Pragma("unroll") for (int mm = 0; mm < 4; ++mm)                           \
        _Pragma("unroll") for (int n = 0; n < 4; ++n) acc[mm][n] =             \
            __builtin_amdgcn_mfma_i32_16x16x64_i8(CUR[mm], bv[n],              \
                                                  acc[mm][n], 0, 0, 0);        \
    __builtin_amdgcn_s_setprio(0);                                             \
    if ((t) + 2 < NT) {                                                        \
      _Pragma("unroll") for (int mm = 0; mm < 4; ++mm)                         \
          CUR[mm] = *(const i32x4*)(apan + (size_t)mm * (16 * D) +             \
                                    ((t) + 2) * 1024);                         \
    }                                                                          \
  } while (0)

  for (int tt = 0; tt < 16; tt += 2) {
    TILE(tt, avA);
    TILE(tt + 1, avB);
  }

  // ---- epilogue: t2 = 2 - 2*dot/S^2; se-term = t2^-5 = d^-10 ----
  // C/D: col = fcol, row = kq*4 + j per 16x16 fragment.
#pragma unroll
  for (int m = 0; m < 4; ++m) {
#pragma unroll
    for (int j = 0; j < 4; ++j) {
      const int rl = wr * 64 + m * 16 + kq * 4 + j;
      const int grow = row0 + rl;
      const int trow = s_tgt[rl];
      float se = 0.f;
#pragma unroll
      for (int n = 0; n < 4; ++n) {
        float dotf = (float)acc[m][n][j];
        float t2 = fmaxf(fmaf(dotf, -2.f / (QSCALE * QSCALE), 2.f), 1e-6f);
        float r = hw_rcp(t2);
        float r2 = r * r;
        float r4 = r2 * r2;
        se += r4 * r;  // t2^-5
        int col = c0 + wc * 64 + n * 16 + fcol;
        if (col == trow) tlp[grow] = (-HEXP * LN2) * hw_log2(sqrtf(t2) + 1e-8f);
      }
#pragma unroll
      for (int off = 8; off >= 1; off >>= 1) se += __shfl_xor(se, off, 64);
      if (fcol == 0) parts[(size_t)grow * (ntN * 2) + tileN * 2 + wc] = se;
    }
  }
}

// ---------------- per-row sum of linear partials + loss ----------------
__global__ __launch_bounds__(256) void k_combine(const float* __restrict__ parts,
                                                 const float* __restrict__ tlp,
                                                 float* __restrict__ rloss, int P) {
  const int row = blockIdx.x;
  const int tid = threadIdx.x;
  const float* p = parts + (size_t)row * P;
  float s = 0.f;
  for (int i = tid; i < P; i += 256) s += p[i];
#pragma unroll
  for (int off = 32; off >= 1; off >>= 1) s += __shfl_xor(s, off, 64);
  __shared__ float ssum[4];
  if ((tid & 63) == 0) ssum[tid >> 6] = s;
  __syncthreads();
  if (tid == 0) {
    float tot = ssum[0] + ssum[1] + ssum[2] + ssum[3];
    float lse = hw_log2(tot) * LN2;
    float pt = hw_exp2((tlp[row] - lse) * RLN2);
    rloss[row] = -hw_log2(pt + 1e-8f) * LN2;
  }
}

// ---------------- mean over rows ----------------
__global__ __launch_bounds__(256) void k_mean(const float* __restrict__ rloss,
                                              float* __restrict__ out, int B) {
  const int tid = threadIdx.x;
  double s = 0.0;
  for (int i = tid; i < B; i += 256) s += (double)rloss[i];
#pragma unroll
  for (int off = 32; off >= 1; off >>= 1) s += __shfl_xor(s, off, 64);
  __shared__ double sd[4];
  if ((tid & 63) == 0) sd[tid >> 6] = s;
  __syncthreads();
  if (tid == 0) out[0] = (float)((sd[0] + sd[1] + sd[2] + sd[3]) / (double)B);
}

extern "C" void kernel_launch(void* const* d_in, const int* in_sizes, int n_in,
                              void* d_out, int out_size, void* d_ws, size_t ws_size,
                              hipStream_t stream) {
  const float* x = (const float*)d_in[0];
  const float* w = (const float*)d_in[1];
  const int* tg = (const int*)d_in[2];
  const int B = in_sizes[2];
  const int D = in_sizes[0] / B;       // 1024
  const int C = in_sizes[1] / D;       // 32000
  const int ntN = C / 128;             // 250

  char* ws = (char*)d_ws;
  unsigned char* xnb = (unsigned char*)ws;                   // B*D i8 (frag-major)
  unsigned char* wnb = xnb + (size_t)B * D;                  // C*D i8 (row-major)
  size_t off = (size_t)B * D + (size_t)C * D;
  off = (off + 255) & ~(size_t)255;
  float* parts = (float*)(ws + off);                         // B * ntN * 2
  off += (size_t)B * ntN * 2 * sizeof(float);
  float* tlp = (float*)(ws + off);                           // B
  off += (size_t)B * sizeof(float);
  float* rloss = (float*)(ws + off);                         // B

  k_rownorm_x<<<B, 256, 0, stream>>>(x, xnb, D);
  k_rownorm_w<<<C, 256, 0, stream>>>(w, wnb, D);
  k_gemm_lse<<<(B / 128) * ntN, 256, 0, stream>>>(xnb, wnb, tg, parts, tlp, B, C, D, ntN);
  k_combine<<<B, 256, 0, stream>>>(parts, tlp, rloss, ntN * 2);
  k_mean<<<1, 256, 0, stream>>>(rloss, (float*)d_out, B);
}

// Round 16
// 228.164 us; speedup vs baseline: 1.3284x; 1.0417x over previous
//
#include <hip/hip_runtime.h>
#include <cstdint>

#define HEXP 10.0f
#define LN2 0.69314718056f
#define RLN2 1.44269504089f
#define QSCALE 500.0f

__device__ __forceinline__ float hw_log2(float x) { return __builtin_amdgcn_logf(x); }
__device__ __forceinline__ float hw_exp2(float x) { return __builtin_amdgcn_exp2f(x); }
__device__ __forceinline__ float hw_rcp(float x) { return __builtin_amdgcn_rcpf(x); }

typedef int i32x4 __attribute__((ext_vector_type(4)));

__device__ __forceinline__ void gl_lds16(const void* g, void* l) {
  __builtin_amdgcn_global_load_lds(
      (const __attribute__((address_space(1))) void*)g,
      (__attribute__((address_space(3))) void*)l, 16, 0, 0);
}

#define BAR() asm volatile("s_barrier" ::: "memory")
#define VM4() asm volatile("s_waitcnt vmcnt(4)" ::: "memory")
#define VM0() asm volatile("s_waitcnt vmcnt(0)" ::: "memory")

// ---- shared normalize+quantize helper (int8, x QSCALE) ----
// |xn_i| <= ~0.17 -> q <= ~87 << 127; dot exact in int32 (<= 7.7M < 2^24).
__device__ __forceinline__ int norm_quant(const float* in, int D, int row,
                                          int tid, float* s4) {
  const float4* inr = (const float4*)(in + (size_t)row * D);
  float4 v = inr[tid];
  float ss = v.x * v.x + v.y * v.y + v.z * v.z + v.w * v.w;
#pragma unroll
  for (int off = 32; off >= 1; off >>= 1) ss += __shfl_xor(ss, off, 64);
  if ((tid & 63) == 0) s4[tid >> 6] = ss;
  __syncthreads();
  float tot = s4[0] + s4[1] + s4[2] + s4[3];
  float scale = QSCALE / fmaxf(sqrtf(tot), 1e-12f);
  int q0 = __float2int_rn(fmaxf(-127.f, fminf(127.f, v.x * scale)));
  int q1 = __float2int_rn(fmaxf(-127.f, fminf(127.f, v.y * scale)));
  int q2 = __float2int_rn(fmaxf(-127.f, fminf(127.f, v.z * scale)));
  int q3 = __float2int_rn(fmaxf(-127.f, fminf(127.f, v.w * scale)));
  return (q0 & 0xff) | ((q1 & 0xff) << 8) | ((q2 & 0xff) << 16) | (q3 << 24);
}

// ------- x rows -> FRAGMENT-MAJOR global A' (R15 verbatim) -------
__global__ __launch_bounds__(256) void k_rownorm_x(const float* __restrict__ in,
                                                   unsigned char* __restrict__ out,
                                                   int D) {
  const int row = blockIdx.x;
  const int tid = threadIdx.x;
  __shared__ float s4[4];
  int w0 = norm_quant(in, D, row, tid, s4);
  const int k0 = tid * 4;
  const size_t doff = (size_t)(row >> 4) * (16 * D) + ((k0 >> 6) << 10) +
                      (((k0 >> 4) & 3) << 8) + ((row & 15) << 4) + (k0 & 15);
  *(int*)(out + doff) = w0;
}

// ------- w rows -> plain row-major (R13 verbatim) -------
__global__ __launch_bounds__(256) void k_rownorm_w(const float* __restrict__ in,
                                                   unsigned char* __restrict__ out,
                                                   int D) {
  const int row = blockIdx.x;
  const int tid = threadIdx.x;
  __shared__ float s4[4];
  int w0 = norm_quant(in, D, row, tid, s4);
  *(int*)(out + (size_t)row * D + tid * 4) = w0;
}

// ------- fused i8 GEMM + harmonic-softmax partials -------
// R15 + BK=128 (NT=8): halves the per-block sync count (barrier skew, VM
// certs, phase entry/exit) while doubling MFMA per sync (32 instr/wave/tile).
// B slot = 2 proven zero-conflict 8KB sub-chunks (geometry/staging verbatim);
// ring-3 = 48KB -> 3 blocks/CU preserved. av (A operands) loaded same-tile
// from fragment-major A' (8 x contiguous-1KB global loads issued right after
// BAR; certified by the body VM4; ~200cy exposure covered by other 2 blocks).
// FIFO vmcnt calendar: top-of-tile VM4 certifies B(t) (allows B(t+1)'s 4);
// body VM4 after av-issue + STAGE_B(t+2) certifies av(t) (allows B(t+2)'s 4).
__global__ __launch_bounds__(256, 3) void k_gemm_lse(
    const unsigned char* __restrict__ xnb,   // fragment-major A'
    const unsigned char* __restrict__ wnb,   // plain row-major
    const int* __restrict__ tgt,
    float* __restrict__ parts,
    float* __restrict__ tlp,
    int M, int C, int D, int ntN) {
  __shared__ __align__(16) unsigned char sB[3][16384];  // 128c x 128k i8
  __shared__ int s_tgt[128];

  const int ntM = M >> 7;               // 32
  const int nwg = ntM * ntN;            // 8000 (div by 8)
  const int orig = blockIdx.x;
  const int cpx = nwg >> 3;
  const int bid = (orig & 7) * cpx + (orig >> 3);   // bijective XCD swizzle
  const int tileM = bid % ntM;
  const int tileN = bid / ntM;
  const int row0 = tileM << 7;
  const int c0 = tileN << 7;

  const int tid = threadIdx.x;
  const int lane = tid & 63;
  const int wid = tid >> 6;             // 0..3
  const int wr = wid >> 1;              // M-half (64 rows)
  const int wc = wid & 1;               // N-half (64 cols)
  const int fcol = lane & 15;
  const int kq = lane >> 4;

  if (tid < 128) s_tgt[tid] = tgt[row0 + tid];

  // B staging lane constants (rule #21 decode, R11/R13 verbatim)
  const int srow_l = lane >> 2;
  const int scol_l = (((lane & 3) ^ ((lane >> 3) & 3)) << 4);
  const int lane16 = lane << 4;
  const size_t Dz = (size_t)D;

  // stage one 8KB sub-chunk (64-k) of B; sub = 0/1 selects k-half of the tile
#define STAGE_B(ds, sub, kb)                                                   \
  do {                                                                         \
    gl_lds16(wnb + (size_t)(c0 + (wid << 5) + srow_l) * Dz + (kb) + scol_l,    \
             sB[ds] + ((sub) << 13) + (wid << 11) + lane16);                   \
    gl_lds16(wnb + (size_t)(c0 + (wid << 5) + 16 + srow_l) * Dz + (kb) +       \
                 scol_l,                                                       \
             sB[ds] + ((sub) << 13) + (wid << 11) + 1024 + lane16);            \
  } while (0)
#define STAGE_BT(ds, tt) do { STAGE_B(ds, 0, (tt)*128); STAGE_B(ds, 1, (tt)*128 + 64); } while (0)

  // B fragment read base within a sub-chunk (zero-conflict, R11/R13 verbatim)
  const int slot16 = ((kq ^ ((fcol >> 1) & 3)) << 4);
  const int bbase = (wc * 64 + fcol) * 64 + slot16;

  // A' direct-load base (R15 verbatim); 64-k frag f at + f*1024
  const unsigned char* apan =
      xnb + (size_t)(tileM * 8 + wr * 4) * (16 * D) + lane16;

  i32x4 acc[4][4];
#pragma unroll
  for (int m = 0; m < 4; ++m)
#pragma unroll
    for (int n = 0; n < 4; ++n) acc[m][n] = (i32x4){0, 0, 0, 0};

  i32x4 av[4][2], bv[4][2];
  const int NT = D >> 7;  // 8 K-tiles of 128

  // prologue: stage B tiles 0,1 (4 gl_lds each per wave)
  STAGE_BT(0, 0);
  STAGE_BT(1, 1);

#pragma unroll
  for (int t = 0; t < 8; ++t) {
    // top cert: queue = [B(t), B(t+1)]; VM4 certifies B(t) cross-wave via BAR
    if (t + 1 < NT) VM4();
    else VM0();
    BAR();
    // issue av(t): 8 contiguous-1KB global loads (completes under body VM4)
#pragma unroll
    for (int mm = 0; mm < 4; ++mm)
#pragma unroll
      for (int h = 0; h < 2; ++h)
        av[mm][h] = *(const i32x4*)(apan + (size_t)mm * (16 * D) +
                                    (2 * t + h) * 1024);
    if (t + 2 < NT) STAGE_BT((t + 2) % 3, t + 2);
    {
      const unsigned char* pB_ = sB[t % 3];
#pragma unroll
      for (int n = 0; n < 4; ++n)
#pragma unroll
        for (int h = 0; h < 2; ++h)
          bv[n][h] = *(const i32x4*)(pB_ + (h << 13) + bbase + n * 1024);
    }
    // body cert: av(t) done (allow B(t+2)'s 4); lgkm for bv is compiler-managed
    if (t + 2 < NT) VM4();
    else VM0();
    __builtin_amdgcn_s_setprio(1);
#pragma unroll
    for (int mm = 0; mm < 4; ++mm)
#pragma unroll
      for (int n = 0; n < 4; ++n)
#pragma unroll
        for (int h = 0; h < 2; ++h)
          acc[mm][n] = __builtin_amdgcn_mfma_i32_16x16x64_i8(
              av[mm][h], bv[n][h], acc[mm][n], 0, 0, 0);
    __builtin_amdgcn_s_setprio(0);
  }

  // ---- epilogue: t2 = 2 - 2*dot/S^2; se-term = t2^-5 = d^-10 ----
  // C/D: col = fcol, row = kq*4 + j per 16x16 fragment.
#pragma unroll
  for (int m = 0; m < 4; ++m) {
#pragma unroll
    for (int j = 0; j < 4; ++j) {
      const int rl = wr * 64 + m * 16 + kq * 4 + j;
      const int grow = row0 + rl;
      const int trow = s_tgt[rl];
      float se = 0.f;
#pragma unroll
      for (int n = 0; n < 4; ++n) {
        float dotf = (float)acc[m][n][j];
        float t2 = fmaxf(fmaf(dotf, -2.f / (QSCALE * QSCALE), 2.f), 1e-6f);
        float r = hw_rcp(t2);
        float r2 = r * r;
        float r4 = r2 * r2;
        se += r4 * r;  // t2^-5
        int col = c0 + wc * 64 + n * 16 + fcol;
        if (col == trow) tlp[grow] = (-HEXP * LN2) * hw_log2(sqrtf(t2) + 1e-8f);
      }
#pragma unroll
      for (int off = 8; off >= 1; off >>= 1) se += __shfl_xor(se, off, 64);
      if (fcol == 0) parts[(size_t)grow * (ntN * 2) + tileN * 2 + wc] = se;
    }
  }
}

// ---------------- per-row sum of linear partials + loss ----------------
__global__ __launch_bounds__(256) void k_combine(const float* __restrict__ parts,
                                                 const float* __restrict__ tlp,
                                                 float* __restrict__ rloss, int P) {
  const int row = blockIdx.x;
  const int tid = threadIdx.x;
  const float* p = parts + (size_t)row * P;
  float s = 0.f;
  for (int i = tid; i < P; i += 256) s += p[i];
#pragma unroll
  for (int off = 32; off >= 1; off >>= 1) s += __shfl_xor(s, off, 64);
  __shared__ float ssum[4];
  if ((tid & 63) == 0) ssum[tid >> 6] = s;
  __syncthreads();
  if (tid == 0) {
    float tot = ssum[0] + ssum[1] + ssum[2] + ssum[3];
    float lse = hw_log2(tot) * LN2;
    float pt = hw_exp2((tlp[row] - lse) * RLN2);
    rloss[row] = -hw_log2(pt + 1e-8f) * LN2;
  }
}

// ---------------- mean over rows ----------------
__global__ __launch_bounds__(256) void k_mean(const float* __restrict__ rloss,
                                              float* __restrict__ out, int B) {
  const int tid = threadIdx.x;
  double s = 0.0;
  for (int i = tid; i < B; i += 256) s += (double)rloss[i];
#pragma unroll
  for (int off = 32; off >= 1; off >>= 1) s += __shfl_xor(s, off, 64);
  __shared__ double sd[4];
  if ((tid & 63) == 0) sd[tid >> 6] = s;
  __syncthreads();
  if (tid == 0) out[0] = (float)((sd[0] + sd[1] + sd[2] + sd[3]) / (double)B);
}

extern "C" void kernel_launch(void* const* d_in, const int* in_sizes, int n_in,
                              void* d_out, int out_size, void* d_ws, size_t ws_size,
                              hipStream_t stream) {
  const float* x = (const float*)d_in[0];
  const float* w = (const float*)d_in[1];
  const int* tg = (const int*)d_in[2];
  const int B = in_sizes[2];
  const int D = in_sizes[0] / B;       // 1024
  const int C = in_sizes[1] / D;       // 32000
  const int ntN = C / 128;             // 250

  char* ws = (char*)d_ws;
  unsigned char* xnb = (unsigned char*)ws;                   // B*D i8 (frag-major)
  unsigned char* wnb = xnb + (size_t)B * D;                  // C*D i8 (row-major)
  size_t off = (size_t)B * D + (size_t)C * D;
  off = (off + 255) & ~(size_t)255;
  float* parts = (float*)(ws + off);                         // B * ntN * 2
  off += (size_t)B * ntN * 2 * sizeof(float);
  float* tlp = (float*)(ws + off);                           // B
  off += (size_t)B * sizeof(float);
  float* rloss = (float*)(ws + off);                         // B

  k_rownorm_x<<<B, 256, 0, stream>>>(x, xnb, D);
  k_rownorm_w<<<C, 256, 0, stream>>>(w, wnb, D);
  k_gemm_lse<<<(B / 128) * ntN, 256, 0, stream>>>(xnb, wnb, tg, parts, tlp, B, C, D, ntN);
  k_combine<<<B, 256, 0, stream>>>(parts, tlp, rloss, ntN * 2);
  k_mean<<<1, 256, 0, stream>>>(rloss, (float*)d_out, B);
}